// Round 2
// baseline (185.535 us; speedup 1.0000x reference)
//
#include <hip/hip_runtime.h>
#include <math.h>

typedef __attribute__((ext_vector_type(8))) short short8;
typedef __attribute__((ext_vector_type(4))) float float4v;

#define D_DIM 256
#define K_EMB 1024
#define HW_SZ 1024
#define N_TOT 32768
#define SMP_B (D_DIM * HW_SZ)  // per-batch stride in X (floats)

// ---- bf16 hi/lo split helpers (RNE) ----
__device__ __forceinline__ unsigned short f2bf(float x) {
  unsigned int u = __builtin_bit_cast(unsigned int, x);
  return (unsigned short)((u + 0x7fffu + ((u >> 16) & 1u)) >> 16);
}
__device__ __forceinline__ float bf2f(unsigned short h) {
  unsigned int u = ((unsigned int)h) << 16;
  return __builtin_bit_cast(float, u);
}

// ---- async global->LDS, 16B/lane (dest = wave-uniform base + lane*16) ----
typedef const __attribute__((address_space(1))) void GV;
typedef __attribute__((address_space(3))) void LV;
__device__ __forceinline__ void async16(const void* g, void* l) {
  __builtin_amdgcn_global_load_lds((GV*)g, (LV*)l, 16, 0, 0);
}

// ------------------------------------------------------------ fused prep ----
// blocks [0,2048): transpose+convert X -> Xh/Xl (bf16 hi/lo, [n][d])
// blocks [2048,2176): convert E -> Ehi/Elo + enorm; block 2048 also zeroes
// counts/lossacc/done (replaces the hipMemsetAsync dispatch).
__global__ __launch_bounds__(256) void vq_prep(
    const float* __restrict__ X, const float* __restrict__ E,
    unsigned short* __restrict__ Xh, unsigned short* __restrict__ Xl,
    unsigned short* __restrict__ Ehi, unsigned short* __restrict__ Elo,
    float* __restrict__ enorm, float* __restrict__ zbase) {
  __shared__ float ts[64][65];  // +1 pad: 2-way-max banks on column reads
  const int t = threadIdx.x;
  const int bi = blockIdx.x;

  if (bi >= 2048) {  // ---- prep E ----
    const int pe = bi - 2048;
    if (pe == 0) {
#pragma unroll
      for (int k = t; k < 1088; k += 256) zbase[k] = 0.f;  // counts+lossa+done
    }
    int tid = pe * 256 + t;  // 32768 threads, 32 per code
    int c = tid >> 5;
    int d0 = (tid & 31) * 8;
    const float* p = E + c * D_DIM + d0;
    float s = 0.f;
    short8 hv, lv;
#pragma unroll
    for (int j = 0; j < 8; ++j) {
      float x = p[j];
      s = fmaf(x, x, s);
      unsigned short h = f2bf(x);
      hv[j] = (short)h;
      lv[j] = (short)f2bf(x - bf2f(h));
    }
    *(short8*)(Ehi + c * D_DIM + d0) = hv;
    *(short8*)(Elo + c * D_DIM + d0) = lv;
#pragma unroll
    for (int off = 1; off <= 16; off <<= 1) s += __shfl_xor(s, off);
    if ((tid & 31) == 0) enorm[c] = s;
    return;
  }

  // ---- prep X: 64d x 64hw tile per block through LDS ----
  const int b = bi >> 6;
  const int dt = (bi >> 4) & 3;
  const int ht = bi & 15;
  const int d0 = dt * 64;
  const int hw0 = ht * 64;
  {
    const int dl = t >> 4;
    const int hl = (t & 15) * 4;
#pragma unroll
    for (int i = 0; i < 4; ++i) {
      float4 v = *(const float4*)(X + b * SMP_B + (d0 + dl + i * 16) * HW_SZ + hw0 + hl);
      ts[dl + i * 16][hl + 0] = v.x;
      ts[dl + i * 16][hl + 1] = v.y;
      ts[dl + i * 16][hl + 2] = v.z;
      ts[dl + i * 16][hl + 3] = v.w;
    }
  }
  __syncthreads();
#pragma unroll
  for (int p = 0; p < 2; ++p) {
    const int c = t + p * 256;
    const int dch = c & 7;   // d chunk of 8
    const int nl = c >> 3;   // 0..63
    short8 hv, lv;
#pragma unroll
    for (int j = 0; j < 8; ++j) {
      float x = ts[dch * 8 + j][nl];
      unsigned short h = f2bf(x);
      hv[j] = (short)h;
      lv[j] = (short)f2bf(x - bf2f(h));
    }
    const int n = b * 1024 + hw0 + nl;
    *(short8*)(Xh + n * D_DIM + d0 + dch * 8) = hv;
    *(short8*)(Xl + n * D_DIM + d0 + dch * 8) = lv;
  }
}

// ------------------------------------------------------------------ gemm ----
// v3: phase-split schedule (T3+T4 prerequisite for T2/T5 to pay).
// Block: 512 threads = 8 waves (2 code-halves x 4 sample-quarters).
// Tile: BM=128 codes x BN=256 samples, BK=32, D=256 -> 8 K-steps.
// Per K-step, 3 phases (one per hi/lo MFMA pass):
//   {ds_read frags ; issue 2 prefetch global_load_lds ; [vmcnt counted] ;
//    s_barrier ; lgkmcnt(0)+sched_barrier ; setprio(1) 16xMFMA setprio(0) ;
//    s_barrier}
// vmcnt(2) only at phase 1 (counted, never 0 mid-loop): the 2 E-prefetch
// loads stay in flight across the barrier. Buffer hazards: every read of a
// buffer is lgkmcnt(0)-drained before the step's trailing barrier; the
// overwriting STAGE for that buffer is issued only after that barrier.
// LDS: (E 16KB + X 32KB) x 2buf = 96KB + 4KB argmin -> 1 block/CU, 8 waves.
// T2 chunk swizzle kept (conflicts measured 0): stored chunk = slot ^
// ((row>>1)&3), inverse-permuted global source, same XOR on reads.
__global__ __launch_bounds__(512, 2) void vq_gemm(
    const unsigned short* __restrict__ Xh, const unsigned short* __restrict__ Xl,
    const unsigned short* __restrict__ Ehi, const unsigned short* __restrict__ Elo,
    const float* __restrict__ enorm, float* __restrict__ pval, int* __restrict__ pidx) {
  __shared__ unsigned short es_hi[2][4096];  // [buf][128 codes * 32] 8KB/buf
  __shared__ unsigned short es_lo[2][4096];
  __shared__ unsigned short xs_hi[2][8192];  // [buf][256 smps * 32] 16KB/buf
  __shared__ unsigned short xs_lo[2][8192];
  __shared__ float rv[2][256];
  __shared__ int ri[2][256];

  const int t = threadIdx.x;   // 0..511
  const int i = blockIdx.x;    // 0..1023
  const int cblk = i >> 7;     // code stripe 0..7 (consecutive blocks share E stripe)
  const int sblk = i & 127;    // sample block 0..127
  const int n0 = sblk * 256;

  const int lane = t & 63;
  const int wv = t >> 6;   // 0..7
  const int wm = wv >> 2;  // code half 0..1
  const int wn = wv & 3;   // sample quarter 0..3
  const int l15 = lane & 15;
  const int q = lane >> 4;

  float4v acc[4][4];
#pragma unroll
  for (int a = 0; a < 4; ++a)
#pragma unroll
    for (int c = 0; c < 4; ++c) acc[a][c] = {0.f, 0.f, 0.f, 0.f};

  // staging: thread t owns 16B at LDS byte t*16 of each tile (linear dest);
  // global source column inverse-swizzled: slot (t&3) carries data chunk
  // (t&3)^((row>>1)&3), row = t>>2 (and row+128 for X chunk1: same XOR).
  const int srow = t >> 2;  // 0..127
  const int scol = (((t & 3) ^ ((t >> 3) & 3)) << 3);
  const unsigned short* ehb = Ehi + (cblk * 128 + srow) * D_DIM + scol;
  const unsigned short* elb = Elo + (cblk * 128 + srow) * D_DIM + scol;
  const unsigned short* xhb = Xh + (n0 + srow) * D_DIM + scol;
  const unsigned short* xlb = Xl + (n0 + srow) * D_DIM + scol;
  char* eh_b = (char*)es_hi;
  char* el_b = (char*)es_lo;
  char* xh_b = (char*)xs_hi;
  char* xl_b = (char*)xs_lo;
  const int dst0 = t * 16;

  // fragment-read column: row = ...16*m + l15 -> (row>>1)&3 = (l15>>1)&3
  const int fcol = (q ^ ((l15 >> 1) & 3)) * 8;

#define STAGE_E(buf, dc)                                    \
  do {                                                      \
    async16(ehb + (dc) * 32, eh_b + (buf) * 8192 + dst0);   \
    async16(elb + (dc) * 32, el_b + (buf) * 8192 + dst0);   \
  } while (0)
#define STAGE_XH(buf, dc)                                                     \
  do {                                                                        \
    async16(xhb + (dc) * 32, xh_b + (buf) * 16384 + dst0);                    \
    async16(xhb + 128 * D_DIM + (dc) * 32, xh_b + (buf) * 16384 + 8192 + dst0);\
  } while (0)
#define STAGE_XL(buf, dc)                                                     \
  do {                                                                        \
    async16(xlb + (dc) * 32, xl_b + (buf) * 16384 + dst0);                    \
    async16(xlb + 128 * D_DIM + (dc) * 32, xl_b + (buf) * 16384 + 8192 + dst0);\
  } while (0)

  // prologue: 6 loads in flight for buffer 0
  STAGE_E(0, 0);
  STAGE_XH(0, 0);
  STAGE_XL(0, 0);

#pragma unroll
  for (int dc = 0; dc < 8; ++dc) {
    const int cur = dc & 1;
    const int nxt = cur ^ 1;

    // ---------------- phase 1: ah . xh ----------------
    if (dc < 7) {
      STAGE_E(nxt, dc + 1);  // 2 prefetch stay in flight across the barrier
      asm volatile("s_waitcnt vmcnt(2)" ::: "memory");  // cur's 6 landed
    } else {
      asm volatile("s_waitcnt vmcnt(0)" ::: "memory");
    }
    __builtin_amdgcn_s_barrier();  // all waves' cur-tile writes visible

    short8 ah[4], xh[4];
#pragma unroll
    for (int mi = 0; mi < 4; ++mi) {
      int row = wm * 64 + mi * 16 + l15;
      ah[mi] = *(const short8*)&es_hi[cur][row * 32 + fcol];
    }
#pragma unroll
    for (int ni = 0; ni < 4; ++ni) {
      int row = wn * 64 + ni * 16 + l15;
      xh[ni] = *(const short8*)&xs_hi[cur][row * 32 + fcol];
    }
    asm volatile("s_waitcnt lgkmcnt(0)" ::: "memory");
    __builtin_amdgcn_sched_barrier(0);
    __builtin_amdgcn_s_setprio(1);
#pragma unroll
    for (int mi = 0; mi < 4; ++mi)
#pragma unroll
      for (int ni = 0; ni < 4; ++ni)
        acc[mi][ni] = __builtin_amdgcn_mfma_f32_16x16x32_bf16(ah[mi], xh[ni], acc[mi][ni], 0, 0, 0);
    __builtin_amdgcn_s_setprio(0);
    __builtin_amdgcn_s_barrier();

    // ---------------- phase 2: ah . xl ----------------
    short8 xl[4];
#pragma unroll
    for (int ni = 0; ni < 4; ++ni) {
      int row = wn * 64 + ni * 16 + l15;
      xl[ni] = *(const short8*)&xs_lo[cur][row * 32 + fcol];
    }
    if (dc < 7) STAGE_XH(nxt, dc + 1);
    asm volatile("s_waitcnt lgkmcnt(0)" ::: "memory");
    __builtin_amdgcn_sched_barrier(0);
    __builtin_amdgcn_s_setprio(1);
#pragma unroll
    for (int mi = 0; mi < 4; ++mi)
#pragma unroll
      for (int ni = 0; ni < 4; ++ni)
        acc[mi][ni] = __builtin_amdgcn_mfma_f32_16x16x32_bf16(ah[mi], xl[ni], acc[mi][ni], 0, 0, 0);
    __builtin_amdgcn_s_setprio(0);
    __builtin_amdgcn_s_barrier();

    // ---------------- phase 3: al . xh ----------------
    short8 al[4];
#pragma unroll
    for (int mi = 0; mi < 4; ++mi) {
      int row = wm * 64 + mi * 16 + l15;
      al[mi] = *(const short8*)&es_lo[cur][row * 32 + fcol];
    }
    if (dc < 7) STAGE_XL(nxt, dc + 1);
    asm volatile("s_waitcnt lgkmcnt(0)" ::: "memory");
    __builtin_amdgcn_sched_barrier(0);
    __builtin_amdgcn_s_setprio(1);
#pragma unroll
    for (int mi = 0; mi < 4; ++mi)
#pragma unroll
      for (int ni = 0; ni < 4; ++ni)
        acc[mi][ni] = __builtin_amdgcn_mfma_f32_16x16x32_bf16(al[mi], xh[ni], acc[mi][ni], 0, 0, 0);
    __builtin_amdgcn_s_setprio(0);
    __builtin_amdgcn_s_barrier();  // cur reads drained; next step may overwrite
  }
#undef STAGE_E
#undef STAGE_XH
#undef STAGE_XL

  // ---- per-sample argmin over this block's 128 codes ----
  float en[16];
#pragma unroll
  for (int mi = 0; mi < 4; ++mi)
#pragma unroll
    for (int r = 0; r < 4; ++r)
      en[mi * 4 + r] = enorm[cblk * 128 + wm * 64 + mi * 16 + q * 4 + r];

#pragma unroll
  for (int ni = 0; ni < 4; ++ni) {
    float bv = 1e30f;
    int bc = 0;
#pragma unroll
    for (int mi = 0; mi < 4; ++mi)
#pragma unroll
      for (int r = 0; r < 4; ++r) {
        float v = fmaf(-2.f, acc[mi][ni][r], en[mi * 4 + r]);
        if (v < bv) { bv = v; bc = wm * 64 + mi * 16 + q * 4 + r; }  // ascending c
      }
#pragma unroll
    for (int off = 16; off <= 32; off <<= 1) {  // merge the 4 q-groups
      float ov = __shfl_xor(bv, off);
      int oc = __shfl_xor(bc, off);
      if (ov < bv || (ov == bv && oc < bc)) { bv = ov; bc = oc; }
    }
    if (q == 0) {
      rv[wm][wn * 64 + ni * 16 + l15] = bv;
      ri[wm][wn * 64 + ni * 16 + l15] = cblk * 128 + bc;
    }
  }
  __syncthreads();
  if (t < 256) {  // merge code halves (wm0 codes < wm1 codes: tie keeps wm0)
    float v0 = rv[0][t];
    int c0 = ri[0][t];
    float v1 = rv[1][t];
    int c1 = ri[1][t];
    if (v1 < v0) { v0 = v1; c0 = c1; }
    pval[cblk * N_TOT + sblk * 256 + t] = v0;
    pidx[cblk * N_TOT + sblk * 256 + t] = c0;
  }
}

// ------------------------------------- epilogue (+ fused finalize) ----------
__global__ __launch_bounds__(256) void vq_epi(
    const float* __restrict__ X, const float* __restrict__ E,
    const float* __restrict__ pval, const int* __restrict__ pidx,
    float* __restrict__ out, float* counts, float* lossacc,
    unsigned* done, float* out_tail) {
  __shared__ int best_idx[64];
  __shared__ float es[64][257];  // gathered best-code rows, fp32
  __shared__ float loss_part[4];
  __shared__ unsigned lastf;
  const int t = threadIdx.x;
  const int n0 = blockIdx.x * 64;
  const int b = n0 >> 10;
  const int hw0 = n0 & 1023;

  if (t < 64) {
    int n = n0 + t;
    float bv = 1e30f;
    int bc = 0;
#pragma unroll
    for (int s = 0; s < 8; ++s) {  // ascending stripe = ascending code range
      float v = pval[s * N_TOT + n];
      int c = pidx[s * N_TOT + n];
      if (v < bv || (v == bv && c < bc)) { bv = v; bc = c; }
    }
    best_idx[t] = bc;
    atomicAdd(&counts[bc], 1.0f);
  }
  __syncthreads();

  // gather the 64 best-code E rows into LDS (coalesced 1KB/wave global reads)
#pragma unroll
  for (int i = 0; i < 16; ++i) {
    const int c = t + i * 256;
    const int r = c >> 6;           // wave-uniform row
    const int col = (c & 63) * 4;
    float4 v = *(const float4*)(E + best_idx[r] * D_DIM + col);
    es[r][col + 0] = v.x;
    es[r][col + 1] = v.y;
    es[r][col + 2] = v.z;
    es[r][col + 3] = v.w;
  }
  __syncthreads();

  const int nl4 = (t & 15) * 4;
  const int drow = t >> 4;
  const float* Xp = X + b * SMP_B + hw0 + nl4;
  float* Op = out + b * SMP_B + hw0 + nl4;
  float lsum = 0.f;
#pragma unroll 4
  for (int d = drow; d < D_DIM; d += 16) {
    float4 x = *(const float4*)(Xp + d * HW_SZ);
    float4 qv;
    qv.x = es[nl4 + 0][d];
    qv.y = es[nl4 + 1][d];
    qv.z = es[nl4 + 2][d];
    qv.w = es[nl4 + 3][d];
    *(float4*)(Op + d * HW_SZ) = qv;
    float d0 = qv.x - x.x; lsum = fmaf(d0, d0, lsum);
    float d1 = qv.y - x.y; lsum = fmaf(d1, d1, lsum);
    float d2 = qv.z - x.z; lsum = fmaf(d2, d2, lsum);
    float d3 = qv.w - x.w; lsum = fmaf(d3, d3, lsum);
  }
#pragma unroll
  for (int off = 32; off >= 1; off >>= 1) lsum += __shfl_xor(lsum, off);
  if ((t & 63) == 0) loss_part[t >> 6] = lsum;
  __syncthreads();
  if (t == 0) {
    atomicAdd(lossacc, loss_part[0] + loss_part[1] + loss_part[2] + loss_part[3]);
    __threadfence();  // make this block's counts/loss atomics globally visible
    lastf = (atomicAdd(done, 1u) == 511u);  // last of 512 blocks finalizes
  }
  __syncthreads();

  if (lastf) {  // ---- fused finalize (runs once, after all blocks) ----
    float s = 0.f;
#pragma unroll
    for (int k = t; k < K_EMB; k += 256) {
      // read through the coherent point (XCD L2s are not cross-coherent)
      float c = atomicAdd(&counts[k], 0.0f);
      float p = c * (1.0f / 32768.0f);
      s = fmaf(p, logf(p + 1e-10f), s);
    }
#pragma unroll
    for (int off = 32; off >= 1; off >>= 1) s += __shfl_xor(s, off);
    __syncthreads();  // loss_part reuse
    if ((t & 63) == 0) loss_part[t >> 6] = s;
    __syncthreads();
    if (t == 0) {
      float tot = loss_part[0] + loss_part[1] + loss_part[2] + loss_part[3];
      float L = atomicAdd(lossacc, 0.0f);
      out_tail[0] = 1.25f * L * (1.0f / 8388608.0f);
      out_tail[1] = expf(-tot);
    }
  }
}

// ---------------------------------------------------------------- launch ----
extern "C" void kernel_launch(void* const* d_in, const int* in_sizes, int n_in,
                              void* d_out, int out_size, void* d_ws, size_t ws_size,
                              hipStream_t stream) {
  const float* X = (const float*)d_in[0];  // [32,256,32,32]
  const float* E = (const float*)d_in[1];  // [1024,256]
  float* out = (float*)d_out;              // 8388608 + 2
  float* ws = (float*)d_ws;

  // d_out doubles as scratch for transposed bf16 X (exactly 8388608 floats);
  // vq_epi fully overwrites it afterwards with the real output.
  unsigned short* Xh = (unsigned short*)out;      // [32768][256] bf16
  unsigned short* Xl = Xh + N_TOT * D_DIM;        // [32768][256] bf16

  unsigned short* Ehi = (unsigned short*)ws;  // 262144 bf16 = 131072 floats
  unsigned short* Elo = Ehi + 262144;
  float* enorm = ws + 262144;                 // [1024]
  float* counts = ws + 263168;                // [1024]
  float* lossa = ws + 264192;                 // [1]
  unsigned* done = (unsigned*)(ws + 264200);  // [1] (inside the zeroed span)
  float* pval = ws + 264256;                  // [8*32768]
  int* pidx = (int*)(ws + 264256 + 262144);   // [8*32768]

  vq_prep<<<2176, 256, 0, stream>>>(X, E, Xh, Xl, Ehi, Elo, enorm, counts);
  vq_gemm<<<1024, 512, 0, stream>>>(Xh, Xl, Ehi, Elo, enorm, pval, pidx);
  vq_epi<<<512, 256, 0, stream>>>(X, E, pval, pidx, out, counts, lossa, done,
                                  out + 8388608);
}

// Round 3
// 178.979 us; speedup vs baseline: 1.0366x; 1.0366x over previous
//
#include <hip/hip_runtime.h>
#include <math.h>

typedef __attribute__((ext_vector_type(8))) short short8;
typedef __attribute__((ext_vector_type(4))) float float4v;

#define D_DIM 256
#define K_EMB 1024
#define HW_SZ 1024
#define N_TOT 32768
#define SMP_B (D_DIM * HW_SZ)  // per-batch stride in X (floats)

// ---- bf16 hi/lo split helpers (RNE) ----
__device__ __forceinline__ unsigned short f2bf(float x) {
  unsigned int u = __builtin_bit_cast(unsigned int, x);
  return (unsigned short)((u + 0x7fffu + ((u >> 16) & 1u)) >> 16);
}
__device__ __forceinline__ float bf2f(unsigned short h) {
  unsigned int u = ((unsigned int)h) << 16;
  return __builtin_bit_cast(float, u);
}

// ---- async global->LDS, 16B/lane (dest = wave-uniform base + lane*16) ----
typedef const __attribute__((address_space(1))) void GV;
typedef __attribute__((address_space(3))) void LV;
__device__ __forceinline__ void async16(const void* g, void* l) {
  __builtin_amdgcn_global_load_lds((GV*)g, (LV*)l, 16, 0, 0);
}

// ------------------------------------------------------------ fused prep ----
// blocks [0,2048): transpose+convert X -> Xh/Xl (bf16 hi/lo, [n][d])
// blocks [2048,2176): convert E -> Ehi/Elo + enorm; block 2048 also zeroes
// counts/lossacc/done (replaces the hipMemsetAsync dispatch).
__global__ __launch_bounds__(256) void vq_prep(
    const float* __restrict__ X, const float* __restrict__ E,
    unsigned short* __restrict__ Xh, unsigned short* __restrict__ Xl,
    unsigned short* __restrict__ Ehi, unsigned short* __restrict__ Elo,
    float* __restrict__ enorm, float* __restrict__ zbase) {
  __shared__ float ts[64][65];  // +1 pad: 2-way-max banks on column reads
  const int t = threadIdx.x;
  const int bi = blockIdx.x;

  if (bi >= 2048) {  // ---- prep E ----
    const int pe = bi - 2048;
    if (pe == 0) {
#pragma unroll
      for (int k = t; k < 1088; k += 256) zbase[k] = 0.f;  // counts+lossa+done
    }
    int tid = pe * 256 + t;  // 32768 threads, 32 per code
    int c = tid >> 5;
    int d0 = (tid & 31) * 8;
    const float* p = E + c * D_DIM + d0;
    float s = 0.f;
    short8 hv, lv;
#pragma unroll
    for (int j = 0; j < 8; ++j) {
      float x = p[j];
      s = fmaf(x, x, s);
      unsigned short h = f2bf(x);
      hv[j] = (short)h;
      lv[j] = (short)f2bf(x - bf2f(h));
    }
    *(short8*)(Ehi + c * D_DIM + d0) = hv;
    *(short8*)(Elo + c * D_DIM + d0) = lv;
#pragma unroll
    for (int off = 1; off <= 16; off <<= 1) s += __shfl_xor(s, off);
    if ((tid & 31) == 0) enorm[c] = s;
    return;
  }

  // ---- prep X: 64d x 64hw tile per block through LDS ----
  const int b = bi >> 6;
  const int dt = (bi >> 4) & 3;
  const int ht = bi & 15;
  const int d0 = dt * 64;
  const int hw0 = ht * 64;
  {
    const int dl = t >> 4;
    const int hl = (t & 15) * 4;
#pragma unroll
    for (int i = 0; i < 4; ++i) {
      float4 v = *(const float4*)(X + b * SMP_B + (d0 + dl + i * 16) * HW_SZ + hw0 + hl);
      ts[dl + i * 16][hl + 0] = v.x;
      ts[dl + i * 16][hl + 1] = v.y;
      ts[dl + i * 16][hl + 2] = v.z;
      ts[dl + i * 16][hl + 3] = v.w;
    }
  }
  __syncthreads();
#pragma unroll
  for (int p = 0; p < 2; ++p) {
    const int c = t + p * 256;
    const int dch = c & 7;   // d chunk of 8
    const int nl = c >> 3;   // 0..63
    short8 hv, lv;
#pragma unroll
    for (int j = 0; j < 8; ++j) {
      float x = ts[dch * 8 + j][nl];
      unsigned short h = f2bf(x);
      hv[j] = (short)h;
      lv[j] = (short)f2bf(x - bf2f(h));
    }
    const int n = b * 1024 + hw0 + nl;
    *(short8*)(Xh + n * D_DIM + d0 + dch * 8) = hv;
    *(short8*)(Xl + n * D_DIM + d0 + dch * 8) = lv;
  }
}

// ------------------------------------------------------------------ gemm ----
// v4 = v0's verified single-buffer 4-wave structure (55.4us) + T2 swizzle
// (conflicts 4.19M -> 0, verified in v1) + 4 blocks/CU via launch_bounds.
// Per block: 128 codes (M) x 128 samples (N), D=256 in BK=32 chunks.
// 3-term MFMA (eh.xh + eh.xl + el.xh); d = enorm - 2S; per-sample argmin
// over the block's 128-code stripe -> partials [8 stripes][32768].
// LDS: 4 tiles x 8KB = 32KB + 1.5KB scratch -> 4 blocks/CU (135KB).
// Overlap model: no explicit dbuf; 4 resident blocks hide each other's
// stage+barrier drain (m114 wave-level overlap).
__global__ __launch_bounds__(256, 4) void vq_gemm(
    const unsigned short* __restrict__ Xh, const unsigned short* __restrict__ Xl,
    const unsigned short* __restrict__ Ehi, const unsigned short* __restrict__ Elo,
    const float* __restrict__ enorm, float* __restrict__ pval, int* __restrict__ pidx) {
  __shared__ unsigned short es_hi[128 * 32];  // 8 KB [code][d-chunk swizzled]
  __shared__ unsigned short es_lo[128 * 32];
  __shared__ unsigned short xs_hi[128 * 32];  // 8 KB [smp][d-chunk swizzled]
  __shared__ unsigned short xs_lo[128 * 32];
  __shared__ float rv[2][128];
  __shared__ int ri[2][128];

  const int t = threadIdx.x;
  const int i = blockIdx.x;
  // XCD-aware swizzle: all 8 code-stripes of one sample-block share i&7 -> same XCD
  const int cblk = (i >> 3) & 7;               // code stripe 0..7
  const int sblk = ((i >> 6) << 3) | (i & 7);  // sample block 0..255
  const int n0 = sblk * 128;

  const int lane = t & 63;
  const int wv = t >> 6;
  const int wm = wv >> 1;  // code half
  const int wn = wv & 1;   // sample half
  const int l15 = lane & 15;
  const int q = lane >> 4;

  float4v acc[4][4];
#pragma unroll
  for (int a = 0; a < 4; ++a)
#pragma unroll
    for (int c = 0; c < 4; ++c) acc[a][c] = {0.f, 0.f, 0.f, 0.f};

  const int srow = t >> 2;  // 0..63 (row within tile half)
  // T2 chunk swizzle: LDS slot (t&3) of row r holds data chunk (t&3)^((r>>1)&3).
  // global_load_lds dest stays LINEAR; the global source column is
  // inverse-permuted per lane ((t>>3)&3 == (srow>>1)&3, same for row+64).
  const int scol = (((t & 3) ^ ((t >> 3) & 3)) << 3);
  const unsigned short* xhb = Xh + (n0 + srow) * D_DIM + scol;
  const unsigned short* xlb = Xl + (n0 + srow) * D_DIM + scol;
  const unsigned short* ehb = Ehi + (cblk * 128 + srow) * D_DIM + scol;
  const unsigned short* elb = Elo + (cblk * 128 + srow) * D_DIM + scol;
  char* xh_b = (char*)xs_hi;
  char* xl_b = (char*)xs_lo;
  char* eh_b = (char*)es_hi;
  char* el_b = (char*)es_lo;
  const int dst0 = t * 16;

  // fragment-read column after swizzle: row = 64*wm + 16*mi + l15
  //   -> (row>>1)&3 = (l15>>1)&3
  const int fcol = (q ^ ((l15 >> 1) & 3)) * 8;

  for (int dc = 0; dc < 8; ++dc) {
    const int d0 = dc * 32;
    async16(xhb + d0, xh_b + dst0);
    async16(xhb + 64 * D_DIM + d0, xh_b + dst0 + 4096);
    async16(xlb + d0, xl_b + dst0);
    async16(xlb + 64 * D_DIM + d0, xl_b + dst0 + 4096);
    async16(ehb + d0, eh_b + dst0);
    async16(ehb + 64 * D_DIM + d0, eh_b + dst0 + 4096);
    async16(elb + d0, el_b + dst0);
    async16(elb + 64 * D_DIM + d0, el_b + dst0 + 4096);
    __syncthreads();  // barrier drains vmcnt -> tiles visible

    short8 ah[4], al[4], xh[4], xl[4];
#pragma unroll
    for (int mi = 0; mi < 4; ++mi) {
      int row = wm * 64 + mi * 16 + l15;
      ah[mi] = *(const short8*)&es_hi[row * 32 + fcol];
      al[mi] = *(const short8*)&es_lo[row * 32 + fcol];
    }
#pragma unroll
    for (int ni = 0; ni < 4; ++ni) {
      int row = wn * 64 + ni * 16 + l15;
      xh[ni] = *(const short8*)&xs_hi[row * 32 + fcol];
      xl[ni] = *(const short8*)&xs_lo[row * 32 + fcol];
    }
#pragma unroll
    for (int mi = 0; mi < 4; ++mi)
#pragma unroll
      for (int ni = 0; ni < 4; ++ni)
        acc[mi][ni] = __builtin_amdgcn_mfma_f32_16x16x32_bf16(ah[mi], xh[ni], acc[mi][ni], 0, 0, 0);
#pragma unroll
    for (int mi = 0; mi < 4; ++mi)
#pragma unroll
      for (int ni = 0; ni < 4; ++ni)
        acc[mi][ni] = __builtin_amdgcn_mfma_f32_16x16x32_bf16(ah[mi], xl[ni], acc[mi][ni], 0, 0, 0);
#pragma unroll
    for (int mi = 0; mi < 4; ++mi)
#pragma unroll
      for (int ni = 0; ni < 4; ++ni)
        acc[mi][ni] = __builtin_amdgcn_mfma_f32_16x16x32_bf16(al[mi], xh[ni], acc[mi][ni], 0, 0, 0);
    __syncthreads();  // all frag reads done before next stage overwrites
  }

  // ---- per-sample argmin over this block's 128 codes ----
  float en[16];
#pragma unroll
  for (int mi = 0; mi < 4; ++mi)
#pragma unroll
    for (int r = 0; r < 4; ++r)
      en[mi * 4 + r] = enorm[cblk * 128 + wm * 64 + mi * 16 + q * 4 + r];

#pragma unroll
  for (int ni = 0; ni < 4; ++ni) {
    float bv = 1e30f;
    int bc = 0;
#pragma unroll
    for (int mi = 0; mi < 4; ++mi)
#pragma unroll
      for (int r = 0; r < 4; ++r) {
        float v = fmaf(-2.f, acc[mi][ni][r], en[mi * 4 + r]);
        if (v < bv) { bv = v; bc = wm * 64 + mi * 16 + q * 4 + r; }  // ascending c
      }
#pragma unroll
    for (int off = 16; off <= 32; off <<= 1) {  // merge the 4 q-groups
      float ov = __shfl_xor(bv, off);
      int oc = __shfl_xor(bc, off);
      if (ov < bv || (ov == bv && oc < bc)) { bv = ov; bc = oc; }
    }
    if (q == 0) {
      rv[wm][wn * 64 + ni * 16 + l15] = bv;
      ri[wm][wn * 64 + ni * 16 + l15] = cblk * 128 + bc;
    }
  }
  __syncthreads();
  if (t < 128) {  // merge code halves (wm0 codes < wm1 codes: tie keeps wm0)
    float v0 = rv[0][t];
    int c0 = ri[0][t];
    float v1 = rv[1][t];
    int c1 = ri[1][t];
    if (v1 < v0) { v0 = v1; c0 = c1; }
    pval[cblk * N_TOT + sblk * 128 + t] = v0;
    pidx[cblk * N_TOT + sblk * 128 + t] = c0;
  }
}

// ------------------------------------- epilogue (+ fused finalize) ----------
__global__ __launch_bounds__(256) void vq_epi(
    const float* __restrict__ X, const float* __restrict__ E,
    const float* __restrict__ pval, const int* __restrict__ pidx,
    float* __restrict__ out, float* counts, float* lossacc,
    unsigned* done, float* out_tail) {
  __shared__ int best_idx[64];
  __shared__ float es[64][257];  // gathered best-code rows, fp32
  __shared__ float loss_part[4];
  __shared__ unsigned lastf;
  const int t = threadIdx.x;
  const int n0 = blockIdx.x * 64;
  const int b = n0 >> 10;
  const int hw0 = n0 & 1023;

  if (t < 64) {
    int n = n0 + t;
    float bv = 1e30f;
    int bc = 0;
#pragma unroll
    for (int s = 0; s < 8; ++s) {  // ascending stripe = ascending code range
      float v = pval[s * N_TOT + n];
      int c = pidx[s * N_TOT + n];
      if (v < bv || (v == bv && c < bc)) { bv = v; bc = c; }
    }
    best_idx[t] = bc;
    atomicAdd(&counts[bc], 1.0f);
  }
  __syncthreads();

  // gather the 64 best-code E rows into LDS (coalesced 1KB/wave global reads)
#pragma unroll
  for (int i = 0; i < 16; ++i) {
    const int c = t + i * 256;
    const int r = c >> 6;           // wave-uniform row
    const int col = (c & 63) * 4;
    float4 v = *(const float4*)(E + best_idx[r] * D_DIM + col);
    es[r][col + 0] = v.x;
    es[r][col + 1] = v.y;
    es[r][col + 2] = v.z;
    es[r][col + 3] = v.w;
  }
  __syncthreads();

  const int nl4 = (t & 15) * 4;
  const int drow = t >> 4;
  const float* Xp = X + b * SMP_B + hw0 + nl4;
  float* Op = out + b * SMP_B + hw0 + nl4;
  float lsum = 0.f;
#pragma unroll 4
  for (int d = drow; d < D_DIM; d += 16) {
    float4 x = *(const float4*)(Xp + d * HW_SZ);
    float4 qv;
    qv.x = es[nl4 + 0][d];
    qv.y = es[nl4 + 1][d];
    qv.z = es[nl4 + 2][d];
    qv.w = es[nl4 + 3][d];
    *(float4*)(Op + d * HW_SZ) = qv;
    float d0 = qv.x - x.x; lsum = fmaf(d0, d0, lsum);
    float d1 = qv.y - x.y; lsum = fmaf(d1, d1, lsum);
    float d2 = qv.z - x.z; lsum = fmaf(d2, d2, lsum);
    float d3 = qv.w - x.w; lsum = fmaf(d3, d3, lsum);
  }
#pragma unroll
  for (int off = 32; off >= 1; off >>= 1) lsum += __shfl_xor(lsum, off);
  if ((t & 63) == 0) loss_part[t >> 6] = lsum;
  __syncthreads();
  if (t == 0) {
    atomicAdd(lossacc, loss_part[0] + loss_part[1] + loss_part[2] + loss_part[3]);
    __threadfence();  // make this block's counts/loss atomics globally visible
    lastf = (atomicAdd(done, 1u) == 511u);  // last of 512 blocks finalizes
  }
  __syncthreads();

  if (lastf) {  // ---- fused finalize (runs once, after all blocks) ----
    float s = 0.f;
#pragma unroll
    for (int k = t; k < K_EMB; k += 256) {
      // read through the coherent point (XCD L2s are not cross-coherent)
      float c = atomicAdd(&counts[k], 0.0f);
      float p = c * (1.0f / 32768.0f);
      s = fmaf(p, logf(p + 1e-10f), s);
    }
#pragma unroll
    for (int off = 32; off >= 1; off >>= 1) s += __shfl_xor(s, off);
    __syncthreads();  // loss_part reuse
    if ((t & 63) == 0) loss_part[t >> 6] = s;
    __syncthreads();
    if (t == 0) {
      float tot = loss_part[0] + loss_part[1] + loss_part[2] + loss_part[3];
      float L = atomicAdd(lossacc, 0.0f);
      out_tail[0] = 1.25f * L * (1.0f / 8388608.0f);
      out_tail[1] = expf(-tot);
    }
  }
}

// ---------------------------------------------------------------- launch ----
extern "C" void kernel_launch(void* const* d_in, const int* in_sizes, int n_in,
                              void* d_out, int out_size, void* d_ws, size_t ws_size,
                              hipStream_t stream) {
  const float* X = (const float*)d_in[0];  // [32,256,32,32]
  const float* E = (const float*)d_in[1];  // [1024,256]
  float* out = (float*)d_out;              // 8388608 + 2
  float* ws = (float*)d_ws;

  // d_out doubles as scratch for transposed bf16 X (exactly 8388608 floats);
  // vq_epi fully overwrites it afterwards with the real output.
  unsigned short* Xh = (unsigned short*)out;      // [32768][256] bf16
  unsigned short* Xl = Xh + N_TOT * D_DIM;        // [32768][256] bf16

  unsigned short* Ehi = (unsigned short*)ws;  // 262144 bf16 = 131072 floats
  unsigned short* Elo = Ehi + 262144;
  float* enorm = ws + 262144;                 // [1024]
  float* counts = ws + 263168;                // [1024]
  float* lossa = ws + 264192;                 // [1]
  unsigned* done = (unsigned*)(ws + 264200);  // [1] (inside the zeroed span)
  float* pval = ws + 264256;                  // [8*32768]
  int* pidx = (int*)(ws + 264256 + 262144);   // [8*32768]

  vq_prep<<<2176, 256, 0, stream>>>(X, E, Xh, Xl, Ehi, Elo, enorm, counts);
  vq_gemm<<<2048, 256, 0, stream>>>(Xh, Xl, Ehi, Elo, enorm, pval, pidx);
  vq_epi<<<512, 256, 0, stream>>>(X, E, pval, pidx, out, counts, lossa, done,
                                  out + 8388608);
}